// Round 18
// baseline (270.393 us; speedup 1.0000x reference)
//
#include <hip/hip_runtime.h>

typedef __attribute__((ext_vector_type(8))) short short8;
typedef __attribute__((ext_vector_type(4))) float f32x4;
typedef unsigned short u16;
typedef unsigned int u32;

#define DEVI __device__ __forceinline__

DEVI u16 f2b(float f) {
  u32 u = __float_as_uint(f);
  u32 r = u + 0x7FFFu + ((u >> 16) & 1u);   // RNE to bf16
  return (u16)(r >> 16);
}
DEVI float b2f(u16 h) { return __uint_as_float(((u32)h) << 16); }
DEVI float silu(float g) { return g / (1.f + __expf(-g)); }

constexpr int T_ = 8192, D_ = 1024, E_ = 16, F_ = 512, FS_ = 2048;

// ---------------- workspace layout (bytes) ----------------
constexpr size_t OFF_XB   = 0;                                   // x bf16 [T][D]
constexpr size_t OFF_WGU  = OFF_XB  + (size_t)T_ * D_ * 2;       // [E][2F][D] gate/up interleaved by 16
constexpr size_t OFF_WDT  = OFF_WGU + (size_t)E_ * 2 * F_ * D_ * 2; // [E][D][F]
constexpr size_t OFF_SGU  = OFF_WDT + (size_t)E_ * D_ * F_ * 2;  // [2FS][D]
constexpr size_t OFF_SDT  = OFF_SGU + (size_t)2 * FS_ * D_ * 2;  // [D][FS]
constexpr size_t OFF_HB   = OFF_SDT + (size_t)D_ * FS_ * 2;      // hbuf bf16 [2T][F]
constexpr size_t OFF_HS   = OFF_HB  + (size_t)2 * T_ * F_ * 2;   // hs bf16 [T][FS]
constexpr size_t OFF_PAIR = OFF_HS  + (size_t)T_ * FS_ * 2;      // pair bf16 [2T][D]
constexpr size_t OFF_PW   = OFF_PAIR + (size_t)2 * T_ * D_ * 2;  // pw f32 [2T]
constexpr size_t OFF_GATE = OFF_PW  + (size_t)2 * T_ * 4;        // gate f32 [T]
constexpr size_t OFF_CNT  = OFF_GATE + (size_t)T_ * 4;           // counts i32 [E]
constexpr size_t OFF_TOP2 = OFF_CNT + 64;                        // top2e i32 [T]
constexpr size_t OFF_LIST = OFF_TOP2 + (size_t)T_ * 4;           // lists i32 [E][T]

// ---------------- fused prep: router (blocks 0..2047) FIRST, then transposes --
__global__ void prep_kernel(
    const float4* __restrict__ x4, const float4* __restrict__ rw4,
    const float4* __restrict__ sgw4, int* __restrict__ top2e,
    float* __restrict__ pw, float* __restrict__ gate, ushort4* __restrict__ xb4,
    const float* __restrict__ Wg, const float* __restrict__ Wu, const float* __restrict__ Wd,
    const float* __restrict__ Sg, const float* __restrict__ Su, const float* __restrict__ Sd,
    u16* __restrict__ wgu, u16* __restrict__ wdT,
    u16* __restrict__ sgu, u16* __restrict__ sdT) {
  const int tid = threadIdx.x;
  const int bid = blockIdx.x;
  if (bid < 2048) {
    // ---- router: 1 token per wave ----
    const int lane = tid & 63, wid = tid >> 6;
    const int t = bid * 4 + wid;
    const float4* xr = x4 + (size_t)t * (D_ / 4);
    float acc[17];
#pragma unroll
    for (int e = 0; e < 17; ++e) acc[e] = 0.f;
    ushort4 xo[4];
#pragma unroll
    for (int j = 0; j < 4; ++j) {
      const int d4 = j * 64 + lane;
      float4 xv = xr[d4];
      xo[j] = make_ushort4(f2b(xv.x), f2b(xv.y), f2b(xv.z), f2b(xv.w));
#pragma unroll
      for (int e = 0; e < 16; ++e) {
        float4 wv = rw4[e * 256 + d4];
        acc[e] = fmaf(xv.x, wv.x, fmaf(xv.y, wv.y, fmaf(xv.z, wv.z, fmaf(xv.w, wv.w, acc[e]))));
      }
      float4 sv = sgw4[d4];
      acc[16] = fmaf(xv.x, sv.x, fmaf(xv.y, sv.y, fmaf(xv.z, sv.z, fmaf(xv.w, sv.w, acc[16]))));
    }
#pragma unroll
    for (int j = 0; j < 4; ++j)
      xb4[(size_t)t * 256 + j * 64 + lane] = xo[j];
#pragma unroll
    for (int e = 0; e < 17; ++e) {
      float v = acc[e];
#pragma unroll
      for (int off = 32; off; off >>= 1) v += __shfl_xor(v, off);
      acc[e] = v;
    }
    if (lane == 0) {
      int i1 = 0; float l1 = acc[0];
#pragma unroll
      for (int e = 1; e < 16; ++e) if (acc[e] > l1) { l1 = acc[e]; i1 = e; }
      int i2 = (i1 == 0) ? 1 : 0; float l2 = acc[i2];
#pragma unroll
      for (int e = 0; e < 16; ++e) {
        if (e == i1) continue;
        if (acc[e] > l2) { l2 = acc[e]; i2 = e; }
      }
      float w1 = 1.f / (1.f + expf(l2 - l1));
      top2e[t] = i1 | (i2 << 8);
      pw[2 * t] = w1;
      pw[2 * t + 1] = 1.f - w1;
      gate[t] = 1.f / (1.f + expf(-acc[16]));
    }
    return;
  }
  // ---- weight transposes: 64x64 tiles, float4 loads, 16B stores ----
  __shared__ float lds[64][65];
  int i = bid - 2048;
  const float* in; u16* out; int R, C, mode, rem;
  if (i < 6144) {
    int j = i >> 11; rem = i & 2047;
    int b = rem >> 7; rem &= 127;
    if (j == 0)      { in = Wg + (size_t)b * D_ * F_; out = wgu + (size_t)b * 2 * F_ * D_; R = D_; C = F_;  mode = 0; }
    else if (j == 1) { in = Wu + (size_t)b * D_ * F_; out = wgu + (size_t)b * 2 * F_ * D_; R = D_; C = F_;  mode = 1; }
    else             { in = Wd + (size_t)b * F_ * D_; out = wdT + (size_t)b * D_ * F_;     R = F_; C = D_;  mode = 2; }
  } else {
    int r2 = i - 6144; int j = r2 >> 9; rem = r2 & 511;
    if (j == 0)      { in = Sg; out = sgu; R = D_;  C = FS_; mode = 0; }
    else if (j == 1) { in = Su; out = sgu; R = D_;  C = FS_; mode = 1; }
    else             { in = Sd; out = sdT; R = FS_; C = D_;  mode = 2; }
  }
  const int ntx = C >> 6;
  const int cx = rem % ntx, cy = rem / ntx;
  const int c0 = cx * 64, r0 = cy * 64;
  {
    const int tx4 = (tid & 15) * 4, ty = tid >> 4;
#pragma unroll
    for (int p = 0; p < 4; ++p) {
      const int rr = ty + p * 16;
      float4 v = *(const float4*)&in[(size_t)(r0 + rr) * C + c0 + tx4];
      lds[rr][tx4] = v.x; lds[rr][tx4 + 1] = v.y; lds[rr][tx4 + 2] = v.z; lds[rr][tx4 + 3] = v.w;
    }
  }
  __syncthreads();
  {
    const int ol = tid >> 2, seg = tid & 3;
    const int f = c0 + ol;
    size_t orow;
    if (mode == 2) orow = f;
    else orow = (size_t)((f >> 4) << 5) + (f & 15) + (mode == 1 ? 16 : 0);
    u16 vals[16];
#pragma unroll
    for (int k = 0; k < 16; ++k) vals[k] = f2b(lds[seg * 16 + k][ol]);
    u16* dst = out + orow * R + r0 + seg * 16;
    *(short8*)dst = *(short8*)&vals[0];
    *(short8*)(dst + 8) = *(short8*)&vals[8];
  }
}

// ---------------- compaction (token-ordered, atomic-free; 1024 threads) -------
__global__ __launch_bounds__(1024) void compact_kernel(
    const int* __restrict__ top2e, int* __restrict__ lists, int* __restrict__ counts) {
  const int e = blockIdx.x;
  const int tid = threadIdx.x, lane = tid & 63, wid = tid >> 6;   // 16 waves
  __shared__ int wsum[16];
  __shared__ int base;
  if (tid == 0) base = 0;
  __syncthreads();
  for (int c0 = 0; c0 < T_; c0 += 1024) {
    const int t = c0 + tid;
    const int pk = top2e[t];
    int slot = -1;
    if ((pk & 0xFF) == e) slot = 2 * t;
    else if (((pk >> 8) & 0xFF) == e) slot = 2 * t + 1;
    const unsigned long long m = __ballot(slot >= 0);
    const int myofs = __popcll(m & ((1ULL << lane) - 1ULL));
    if (lane == 0) wsum[wid] = __popcll(m);
    __syncthreads();
    const int b = base;
    int wbase = 0;
#pragma unroll
    for (int w = 0; w < 16; ++w) if (w < wid) wbase += wsum[w];
    if (slot >= 0) lists[e * T_ + b + wbase + myofs] = slot;
    __syncthreads();
    if (tid == 0) {
      int s = 0;
#pragma unroll
      for (int w = 0; w < 16; ++w) s += wsum[w];
      base += s;
    }
    __syncthreads();
  }
  if (tid == 0) counts[e] = base;
}

// ---------------- GEMM cores: 128x128 tile, BK=64, 4 waves -------------------
// Schedule matched to occupancy regime:
//  - gu/down1 (grid >= 4 blocks/CU): single 32KB buffer, (256,4) — r14: 880 TF.
//  - down3 (512 blocks = 2/CU): dbuf 2-phase (256,2) — r16 confirmed.
// r18: gu expert tiles mt-fastest (B-panel L2 reuse; B=2MB/expert > A=256KB).
// Measured-harmful: XCD swizzle (r7), 256^2 (r9), coarse vmcnt (r11),
// A-in-reg (r13), over-tight launch_bounds (r15: VGPR 60->48 spills).
DEVI void gl_lds16(const void* gsrc, void* lds) {
  __builtin_amdgcn_global_load_lds((const __attribute__((address_space(1))) unsigned int*)gsrc,
                                   (__attribute__((address_space(3))) unsigned int*)lds, 16, 0, 0);
}

DEVI void prefix16(const int* counts, int e, int& cnt, int& roff) {
  cnt = counts[e];
  int s = 0;
#pragma unroll
  for (int k = 0; k < E_; ++k) s += (k < e) ? counts[k] : 0;
  roff = s;
}

// fused gate+up GEMM with interleaved B' (N'=2F per expert / 2FS shared).
// bid [0,2048): expert e=bid>>7; r=bid&127; mt=r&15 (FASTEST), nt=r>>4 (0..7)
// bid [2048,4096): shared st=bid-2048, mt=st&63 (fastest), nt=st>>6 (0..15)
__global__ __launch_bounds__(256, 4) void gu_gemm(
    const u16* __restrict__ xb, const u16* __restrict__ wgu, const u16* __restrict__ sgu,
    u16* __restrict__ hb, u16* __restrict__ hs,
    const int* __restrict__ counts, const int* __restrict__ lists) {
  extern __shared__ char smem[];
  const int tid = threadIdx.x;
  const int bid = blockIdx.x;
  const bool se = (bid >= 2048);
  int mt, nt, e = 0, cnt = 0, roff = 0;
  const u16* B0;
  if (!se) {
    e = bid >> 7; int r = bid & 127; mt = r & 15; nt = r >> 4;
    prefix16(counts, e, cnt, roff);
    if (mt * 128 >= cnt) return;
    B0 = wgu + (size_t)e * 2 * F_ * D_;
  } else {
    int st = bid - 2048;
    mt = st & 63; nt = st >> 6;
    B0 = sgu;
  }

  const int lane = tid & 63, wid = tid >> 6;
  const int wm = wid >> 1, wn = wid & 1;
  const int lr = lane & 15, lg = lane >> 4;
  const int ldsrow = tid >> 3;
  const int kslot = (tid & 7) << 4;
  constexpr size_t strideB = (size_t)D_ * 2;
  const char* aSrc[4]; const char* bSrc[4];
#pragma unroll
  for (int q = 0; q < 4; ++q) {
    int row = q * 32 + ldsrow;
    int kb = kslot ^ ((row & 7) << 4);
    int r = mt * 128 + row;
    long arow;
    if (!se) arow = (r < cnt) ? (lists[e * T_ + r] >> 1) : 0;
    else arow = r;
    aSrc[q] = (const char*)xb + (size_t)arow * strideB + kb;
    int nrow = nt * 128 + row;
    bSrc[q] = (const char*)B0 + (size_t)nrow * strideB + kb;
  }

  const f32x4 fz = {0.f, 0.f, 0.f, 0.f};
  f32x4 acc[4][4];
#pragma unroll
  for (int i = 0; i < 4; ++i)
#pragma unroll
    for (int j = 0; j < 4; ++j) acc[i][j] = fz;

  const int sw = (lr & 7) << 4;
  constexpr int nks = D_ / 64;   // 16

  for (int ks = 0; ks < nks; ++ks) {
    const int kbo = ks * 128;
#pragma unroll
    for (int q = 0; q < 4; ++q) gl_lds16(aSrc[q] + kbo, smem + q * 4096 + tid * 16);
#pragma unroll
    for (int q = 0; q < 4; ++q) gl_lds16(bSrc[q] + kbo, smem + 16384 + q * 4096 + tid * 16);
    __syncthreads();
    const char* As = smem;
    const char* Bs = smem + 16384;
#pragma unroll
    for (int kk = 0; kk < 2; ++kk) {
      const int ko = kk * 64 + lg * 16;
      short8 af[4];
#pragma unroll
      for (int fm = 0; fm < 4; ++fm) {
        int row = wm * 64 + fm * 16 + lr;
        af[fm] = *(const short8*)(As + row * 128 + (ko ^ sw));
      }
#pragma unroll
      for (int fn = 0; fn < 4; ++fn) {
        int col = wn * 64 + fn * 16 + lr;
        short8 bf = *(const short8*)(Bs + col * 128 + (ko ^ sw));
#pragma unroll
        for (int fm = 0; fm < 4; ++fm)
          acc[fm][fn] = __builtin_amdgcn_mfma_f32_16x16x32_bf16(af[fm], bf, acc[fm][fn], 0, 0, 0);
      }
    }
    __syncthreads();
  }

  const int c0 = 16 * (4 * nt + 2 * wn);
  const int r0 = mt * 128;
#pragma unroll
  for (int fm = 0; fm < 4; ++fm) {
#pragma unroll
    for (int j = 0; j < 4; ++j) {
      const int r = r0 + wm * 64 + fm * 16 + lg * 4 + j;
      if (!se && r >= cnt) continue;
      float h0 = silu(acc[fm][0][j]) * acc[fm][1][j];
      float h1 = silu(acc[fm][2][j]) * acc[fm][3][j];
      if (!se) {
        hb[(size_t)(roff + r) * F_ + c0 + lr] = f2b(h0);
        hb[(size_t)(roff + r) * F_ + c0 + 16 + lr] = f2b(h1);
      } else {
        hs[(size_t)r * FS_ + c0 + lr] = f2b(h0);
        hs[(size_t)r * FS_ + c0 + 16 + lr] = f2b(h1);
      }
    }
  }
}

// MODE 1: expert down (single buffer, (256,4)).
// MODE 3: shared down + combine (dbuf 2-phase, (256,2): grid 512 = 2 blocks/CU).
template <int MODE>
__global__ __launch_bounds__(256, MODE == 3 ? 2 : 4) void moe_gemm(
    const u16* __restrict__ Abase, const u16* __restrict__ B0,
    u16* __restrict__ outb, float* __restrict__ outf,
    const int* __restrict__ counts, const int* __restrict__ lists,
    const float* __restrict__ pw, const float* __restrict__ gate,
    const u16* __restrict__ pairb, int Kdim) {
  extern __shared__ char smem[];
  const int tid = threadIdx.x;
  const int mt = blockIdx.x, nt = blockIdx.y, e = blockIdx.z;

  int cnt = 0;
  const u16* A = Abase;
  if constexpr (MODE == 1) {
    int roff;
    prefix16(counts, e, cnt, roff);
    if (mt * 128 >= cnt) return;
    A = Abase + (size_t)roff * Kdim;
    B0 += (size_t)e * D_ * F_;
  }

  const int lane = tid & 63, wid = tid >> 6;
  const int wm = wid >> 1, wn = wid & 1;
  const int lr = lane & 15, lg = lane >> 4;
  const int ldsrow = tid >> 3;
  const int kslot = (tid & 7) << 4;
  const size_t strideB = (size_t)Kdim * 2;
  const char* aSrc[4]; const char* bSrc[4];
#pragma unroll
  for (int q = 0; q < 4; ++q) {
    int row = q * 32 + ldsrow;
    int kb = kslot ^ ((row & 7) << 4);
    long arow;
    if constexpr (MODE == 1) {
      int r = mt * 128 + row;
      arow = (r < cnt) ? r : (cnt - 1);
    } else {
      arow = mt * 128 + row;
    }
    aSrc[q] = (const char*)A + (size_t)arow * strideB + kb;
    int nrow = nt * 128 + row;
    bSrc[q] = (const char*)B0 + (size_t)nrow * strideB + kb;
  }

  const f32x4 fz = {0.f, 0.f, 0.f, 0.f};
  f32x4 acc[4][4];
#pragma unroll
  for (int i = 0; i < 4; ++i)
#pragma unroll
    for (int j = 0; j < 4; ++j) acc[i][j] = fz;

  const int nks = Kdim >> 6;
  const int sw = (lr & 7) << 4;

  if constexpr (MODE == 3) {
    {
      char* dst = smem;
#pragma unroll
      for (int q = 0; q < 4; ++q) gl_lds16(aSrc[q], dst + q * 4096 + tid * 16);
#pragma unroll
      for (int q = 0; q < 4; ++q) gl_lds16(bSrc[q], dst + 16384 + q * 4096 + tid * 16);
    }
    __syncthreads();
    int cur = 0;
    for (int ks = 0; ks < nks; ++ks) {
      if (ks + 1 < nks) {
        const int kbo = (ks + 1) * 128;
        char* dst = smem + (cur ^ 1) * 32768;
#pragma unroll
        for (int q = 0; q < 4; ++q) gl_lds16(aSrc[q] + kbo, dst + q * 4096 + tid * 16);
#pragma unroll
        for (int q = 0; q < 4; ++q) gl_lds16(bSrc[q] + kbo, dst + 16384 + q * 4096 + tid * 16);
      }
      const char* As = smem + cur * 32768;
      const char* Bs = As + 16384;
#pragma unroll
      for (int kk = 0; kk < 2; ++kk) {
        const int ko = kk * 64 + lg * 16;
        short8 af[4];
#pragma unroll
        for (int fm = 0; fm < 4; ++fm) {
          int row = wm * 64 + fm * 16 + lr;
          af[fm] = *(const short8*)(As + row * 128 + (ko ^ sw));
        }
#pragma unroll
        for (int fn = 0; fn < 4; ++fn) {
          int col = wn * 64 + fn * 16 + lr;
          short8 bf = *(const short8*)(Bs + col * 128 + (ko ^ sw));
#pragma unroll
          for (int fm = 0; fm < 4; ++fm)
            acc[fm][fn] = __builtin_amdgcn_mfma_f32_16x16x32_bf16(af[fm], bf, acc[fm][fn], 0, 0, 0);
        }
      }
      __syncthreads();
      cur ^= 1;
    }
  } else {
    for (int ks = 0; ks < nks; ++ks) {
      const int kbo = ks * 128;
#pragma unroll
      for (int q = 0; q < 4; ++q) gl_lds16(aSrc[q] + kbo, smem + q * 4096 + tid * 16);
#pragma unroll
      for (int q = 0; q < 4; ++q) gl_lds16(bSrc[q] + kbo, smem + 16384 + q * 4096 + tid * 16);
      __syncthreads();
      const char* As = smem;
      const char* Bs = smem + 16384;
#pragma unroll
      for (int kk = 0; kk < 2; ++kk) {
        const int ko = kk * 64 + lg * 16;
        short8 af[4];
#pragma unroll
        for (int fm = 0; fm < 4; ++fm) {
          int row = wm * 64 + fm * 16 + lr;
          af[fm] = *(const short8*)(As + row * 128 + (ko ^ sw));
        }
#pragma unroll
        for (int fn = 0; fn < 4; ++fn) {
          int col = wn * 64 + fn * 16 + lr;
          short8 bf = *(const short8*)(Bs + col * 128 + (ko ^ sw));
#pragma unroll
          for (int fm = 0; fm < 4; ++fm)
            acc[fm][fn] = __builtin_amdgcn_mfma_f32_16x16x32_bf16(af[fm], bf, acc[fm][fn], 0, 0, 0);
        }
      }
      __syncthreads();
    }
  }

  const int r0 = mt * 128;
#pragma unroll
  for (int fm = 0; fm < 4; ++fm) {
#pragma unroll
    for (int j = 0; j < 4; ++j) {
      const int rowt = wm * 64 + fm * 16 + lg * 4 + j;
      const int r = r0 + rowt;
      if constexpr (MODE == 1) {
        if (r >= cnt) continue;
      }
      int slot = 0;
      float rsc = 0.f;
      if constexpr (MODE == 1) { slot = lists[e * T_ + r]; rsc = pw[slot]; }
      if constexpr (MODE == 3) rsc = gate[r];
#pragma unroll
      for (int fn = 0; fn < 4; ++fn) {
        const int c = nt * 128 + wn * 64 + fn * 16 + lr;
        float v = acc[fm][fn][j];
        if constexpr (MODE == 1) {
          outb[(size_t)slot * D_ + c] = f2b(rsc * v);
        } else {
          float o = v * rsc + b2f(pairb[(size_t)(2 * r) * D_ + c]) + b2f(pairb[(size_t)(2 * r + 1) * D_ + c]);
          outf[(size_t)r * D_ + c] = o;
        }
      }
    }
  }
}

// ---------------- launch ----------------
extern "C" void kernel_launch(void* const* d_in, const int* in_sizes, int n_in,
                              void* d_out, int out_size, void* d_ws, size_t ws_size,
                              hipStream_t stream) {
  const float* x   = (const float*)d_in[0];
  const float* rw  = (const float*)d_in[1];
  const float* Wg  = (const float*)d_in[2];
  const float* Wu  = (const float*)d_in[3];
  const float* Wd  = (const float*)d_in[4];
  const float* Sg  = (const float*)d_in[5];
  const float* Su  = (const float*)d_in[6];
  const float* Sd  = (const float*)d_in[7];
  const float* sgw = (const float*)d_in[8];
  float* out = (float*)d_out;

  unsigned char* ws = (unsigned char*)d_ws;
  u16* xb    = (u16*)(ws + OFF_XB);
  u16* wgu   = (u16*)(ws + OFF_WGU);
  u16* wdT   = (u16*)(ws + OFF_WDT);
  u16* sgu   = (u16*)(ws + OFF_SGU);
  u16* sdT   = (u16*)(ws + OFF_SDT);
  u16* hb    = (u16*)(ws + OFF_HB);
  u16* hs    = (u16*)(ws + OFF_HS);
  u16* pairb = (u16*)(ws + OFF_PAIR);
  float* pwf   = (float*)(ws + OFF_PW);
  float* gatef = (float*)(ws + OFF_GATE);
  int* cnti    = (int*)(ws + OFF_CNT);
  int* top2i   = (int*)(ws + OFF_TOP2);
  int* listsi  = (int*)(ws + OFF_LIST);

  prep_kernel<<<9728, 256, 0, stream>>>(
      (const float4*)x, (const float4*)rw, (const float4*)sgw,
      top2i, pwf, gatef, (ushort4*)xb,
      Wg, Wu, Wd, Sg, Su, Sd, wgu, wdT, sgu, sdT);
  compact_kernel<<<E_, 1024, 0, stream>>>(top2i, listsi, cnti);

  // fused gate+up: expert tiles [0,2048), shared [2048,4096). K=1024
  gu_gemm<<<4096, 256, 32768, stream>>>(xb, wgu, sgu, hb, hs, cnti, listsi);
  // expert down: K=512, N=1024 (single buffer)
  moe_gemm<1><<<dim3(16, 8, 16), 256, 32768, stream>>>(hb, wdT, pairb, nullptr,
                                                       cnti, listsi, pwf, gatef, nullptr, 512);
  // shared down + final combine: K=2048, N=1024 (dbuf 2-phase)
  moe_gemm<3><<<dim3(64, 8, 1), 256, 65536, stream>>>(hs, sdT, nullptr, out,
                                                      cnti, listsi, pwf, gatef, pairb, 2048);

  (void)in_sizes; (void)n_in; (void)out_size; (void)ws_size;
}

// Round 19
// 261.676 us; speedup vs baseline: 1.0333x; 1.0333x over previous
//
#include <hip/hip_runtime.h>

typedef __attribute__((ext_vector_type(8))) short short8;
typedef __attribute__((ext_vector_type(4))) float f32x4;
typedef unsigned short u16;
typedef unsigned int u32;

#define DEVI __device__ __forceinline__

DEVI u16 f2b(float f) {
  u32 u = __float_as_uint(f);
  u32 r = u + 0x7FFFu + ((u >> 16) & 1u);   // RNE to bf16
  return (u16)(r >> 16);
}
DEVI float b2f(u16 h) { return __uint_as_float(((u32)h) << 16); }
DEVI float silu(float g) { return g / (1.f + __expf(-g)); }

constexpr int T_ = 8192, D_ = 1024, E_ = 16, F_ = 512, FS_ = 2048;

// ---------------- workspace layout (bytes) ----------------
constexpr size_t OFF_XB   = 0;                                   // x bf16 [T][D]
constexpr size_t OFF_WGU  = OFF_XB  + (size_t)T_ * D_ * 2;       // [E][2F][D] gate/up interleaved by 16
constexpr size_t OFF_WDT  = OFF_WGU + (size_t)E_ * 2 * F_ * D_ * 2; // [E][D][F]
constexpr size_t OFF_SGU  = OFF_WDT + (size_t)E_ * D_ * F_ * 2;  // [2FS][D]
constexpr size_t OFF_SDT  = OFF_SGU + (size_t)2 * FS_ * D_ * 2;  // [D][FS]
constexpr size_t OFF_HB   = OFF_SDT + (size_t)D_ * FS_ * 2;      // hbuf bf16 [2T][F]
constexpr size_t OFF_HS   = OFF_HB  + (size_t)2 * T_ * F_ * 2;   // hs bf16 [T][FS]
constexpr size_t OFF_PAIR = OFF_HS  + (size_t)T_ * FS_ * 2;      // pair bf16 [2T][D]
constexpr size_t OFF_PW   = OFF_PAIR + (size_t)2 * T_ * D_ * 2;  // pw f32 [2T]
constexpr size_t OFF_GATE = OFF_PW  + (size_t)2 * T_ * 4;        // gate f32 [T]
constexpr size_t OFF_CNT  = OFF_GATE + (size_t)T_ * 4;           // counts i32 [E]
constexpr size_t OFF_TOP2 = OFF_CNT + 64;                        // top2e i32 [T]
constexpr size_t OFF_LIST = OFF_TOP2 + (size_t)T_ * 4;           // lists i32 [E][T]

// ---------------- fused prep: router (blocks 0..2047) FIRST, then transposes --
// Router blocks are the slow compute-heavy ones; dispatching them first hides
// their latency under the BW-bound transpose swarm instead of forming a tail.
__global__ void prep_kernel(
    const float4* __restrict__ x4, const float4* __restrict__ rw4,
    const float4* __restrict__ sgw4, int* __restrict__ top2e,
    float* __restrict__ pw, float* __restrict__ gate, ushort4* __restrict__ xb4,
    const float* __restrict__ Wg, const float* __restrict__ Wu, const float* __restrict__ Wd,
    const float* __restrict__ Sg, const float* __restrict__ Su, const float* __restrict__ Sd,
    u16* __restrict__ wgu, u16* __restrict__ wdT,
    u16* __restrict__ sgu, u16* __restrict__ sdT) {
  const int tid = threadIdx.x;
  const int bid = blockIdx.x;
  if (bid < 2048) {
    // ---- router: 1 token per wave ----
    const int lane = tid & 63, wid = tid >> 6;
    const int t = bid * 4 + wid;
    const float4* xr = x4 + (size_t)t * (D_ / 4);
    float acc[17];
#pragma unroll
    for (int e = 0; e < 17; ++e) acc[e] = 0.f;
    ushort4 xo[4];
#pragma unroll
    for (int j = 0; j < 4; ++j) {
      const int d4 = j * 64 + lane;
      float4 xv = xr[d4];
      xo[j] = make_ushort4(f2b(xv.x), f2b(xv.y), f2b(xv.z), f2b(xv.w));
#pragma unroll
      for (int e = 0; e < 16; ++e) {
        float4 wv = rw4[e * 256 + d4];
        acc[e] = fmaf(xv.x, wv.x, fmaf(xv.y, wv.y, fmaf(xv.z, wv.z, fmaf(xv.w, wv.w, acc[e]))));
      }
      float4 sv = sgw4[d4];
      acc[16] = fmaf(xv.x, sv.x, fmaf(xv.y, sv.y, fmaf(xv.z, sv.z, fmaf(xv.w, sv.w, acc[16]))));
    }
#pragma unroll
    for (int j = 0; j < 4; ++j)
      xb4[(size_t)t * 256 + j * 64 + lane] = xo[j];
#pragma unroll
    for (int e = 0; e < 17; ++e) {
      float v = acc[e];
#pragma unroll
      for (int off = 32; off; off >>= 1) v += __shfl_xor(v, off);
      acc[e] = v;
    }
    if (lane == 0) {
      int i1 = 0; float l1 = acc[0];
#pragma unroll
      for (int e = 1; e < 16; ++e) if (acc[e] > l1) { l1 = acc[e]; i1 = e; }
      int i2 = (i1 == 0) ? 1 : 0; float l2 = acc[i2];
#pragma unroll
      for (int e = 0; e < 16; ++e) {
        if (e == i1) continue;
        if (acc[e] > l2) { l2 = acc[e]; i2 = e; }
      }
      float w1 = 1.f / (1.f + expf(l2 - l1));
      top2e[t] = i1 | (i2 << 8);
      pw[2 * t] = w1;
      pw[2 * t + 1] = 1.f - w1;
      gate[t] = 1.f / (1.f + expf(-acc[16]));
    }
    return;
  }
  // ---- weight transposes: 64x64 tiles, float4 loads, 16B stores ----
  __shared__ float lds[64][65];
  int i = bid - 2048;
  const float* in; u16* out; int R, C, mode, rem;
  if (i < 6144) {
    int j = i >> 11; rem = i & 2047;
    int b = rem >> 7; rem &= 127;
    if (j == 0)      { in = Wg + (size_t)b * D_ * F_; out = wgu + (size_t)b * 2 * F_ * D_; R = D_; C = F_;  mode = 0; }
    else if (j == 1) { in = Wu + (size_t)b * D_ * F_; out = wgu + (size_t)b * 2 * F_ * D_; R = D_; C = F_;  mode = 1; }
    else             { in = Wd + (size_t)b * F_ * D_; out = wdT + (size_t)b * D_ * F_;     R = F_; C = D_;  mode = 2; }
  } else {
    int r2 = i - 6144; int j = r2 >> 9; rem = r2 & 511;
    if (j == 0)      { in = Sg; out = sgu; R = D_;  C = FS_; mode = 0; }
    else if (j == 1) { in = Su; out = sgu; R = D_;  C = FS_; mode = 1; }
    else             { in = Sd; out = sdT; R = FS_; C = D_;  mode = 2; }
  }
  const int ntx = C >> 6;
  const int cx = rem % ntx, cy = rem / ntx;
  const int c0 = cx * 64, r0 = cy * 64;
  {
    const int tx4 = (tid & 15) * 4, ty = tid >> 4;
#pragma unroll
    for (int p = 0; p < 4; ++p) {
      const int rr = ty + p * 16;
      float4 v = *(const float4*)&in[(size_t)(r0 + rr) * C + c0 + tx4];
      lds[rr][tx4] = v.x; lds[rr][tx4 + 1] = v.y; lds[rr][tx4 + 2] = v.z; lds[rr][tx4 + 3] = v.w;
    }
  }
  __syncthreads();
  {
    const int ol = tid >> 2, seg = tid & 3;
    const int f = c0 + ol;
    size_t orow;
    if (mode == 2) orow = f;
    else orow = (size_t)((f >> 4) << 5) + (f & 15) + (mode == 1 ? 16 : 0);
    u16 vals[16];
#pragma unroll
    for (int k = 0; k < 16; ++k) vals[k] = f2b(lds[seg * 16 + k][ol]);
    u16* dst = out + orow * R + r0 + seg * 16;
    *(short8*)dst = *(short8*)&vals[0];
    *(short8*)(dst + 8) = *(short8*)&vals[8];
  }
}

// ---------------- compaction (token-ordered, atomic-free; 1024 threads) -------
__global__ __launch_bounds__(1024) void compact_kernel(
    const int* __restrict__ top2e, int* __restrict__ lists, int* __restrict__ counts) {
  const int e = blockIdx.x;
  const int tid = threadIdx.x, lane = tid & 63, wid = tid >> 6;   // 16 waves
  __shared__ int wsum[16];
  __shared__ int base;
  if (tid == 0) base = 0;
  __syncthreads();
  for (int c0 = 0; c0 < T_; c0 += 1024) {
    const int t = c0 + tid;
    const int pk = top2e[t];
    int slot = -1;
    if ((pk & 0xFF) == e) slot = 2 * t;
    else if (((pk >> 8) & 0xFF) == e) slot = 2 * t + 1;
    const unsigned long long m = __ballot(slot >= 0);
    const int myofs = __popcll(m & ((1ULL << lane) - 1ULL));
    if (lane == 0) wsum[wid] = __popcll(m);
    __syncthreads();
    const int b = base;
    int wbase = 0;
#pragma unroll
    for (int w = 0; w < 16; ++w) if (w < wid) wbase += wsum[w];
    if (slot >= 0) lists[e * T_ + b + wbase + myofs] = slot;
    __syncthreads();
    if (tid == 0) {
      int s = 0;
#pragma unroll
      for (int w = 0; w < 16; ++w) s += wsum[w];
      base += s;
    }
    __syncthreads();
  }
  if (tid == 0) counts[e] = base;
}

// ---------------- GEMM cores: 128x128 tile, BK=64, 4 waves -------------------
// Schedule matched to occupancy regime:
//  - gu/down1 (grid >= 4 blocks/CU): single 32KB buffer, (256,4) — r14: 880 TF.
//  - down3 (512 blocks = 2/CU): dbuf 2-phase (256,2) — r16 confirmed.
// Measured-harmful: XCD swizzle (r7), 256^2 (r9), coarse vmcnt (r11),
// A-in-reg (r13), over-tight launch_bounds (r15), mt-fastest order (r18).
DEVI void gl_lds16(const void* gsrc, void* lds) {
  __builtin_amdgcn_global_load_lds((const __attribute__((address_space(1))) unsigned int*)gsrc,
                                   (__attribute__((address_space(3))) unsigned int*)lds, 16, 0, 0);
}

DEVI void prefix16(const int* counts, int e, int& cnt, int& roff) {
  cnt = counts[e];
  int s = 0;
#pragma unroll
  for (int k = 0; k < E_; ++k) s += (k < e) ? counts[k] : 0;
  roff = s;
}

// fused gate+up GEMM with interleaved B' (N'=2F per expert / 2FS shared).
// bid [0,2048): expert e=bid>>7, mt=(bid&127)>>3 (0..15), nt=bid&7 (0..7)
// bid [2048,4096): shared st=bid-2048, mt=st&63, nt=st>>6 (0..31)
__global__ __launch_bounds__(256, 4) void gu_gemm(
    const u16* __restrict__ xb, const u16* __restrict__ wgu, const u16* __restrict__ sgu,
    u16* __restrict__ hb, u16* __restrict__ hs,
    const int* __restrict__ counts, const int* __restrict__ lists) {
  extern __shared__ char smem[];
  const int tid = threadIdx.x;
  const int bid = blockIdx.x;
  const bool se = (bid >= 2048);
  int mt, nt, e = 0, cnt = 0, roff = 0;
  const u16* B0;
  if (!se) {
    e = bid >> 7; int r = bid & 127; mt = r >> 3; nt = r & 7;
    prefix16(counts, e, cnt, roff);
    if (mt * 128 >= cnt) return;
    B0 = wgu + (size_t)e * 2 * F_ * D_;
  } else {
    int st = bid - 2048;
    mt = st & 63; nt = st >> 6;
    B0 = sgu;
  }

  const int lane = tid & 63, wid = tid >> 6;
  const int wm = wid >> 1, wn = wid & 1;
  const int lr = lane & 15, lg = lane >> 4;
  const int ldsrow = tid >> 3;
  const int kslot = (tid & 7) << 4;
  constexpr size_t strideB = (size_t)D_ * 2;
  const char* aSrc[4]; const char* bSrc[4];
#pragma unroll
  for (int q = 0; q < 4; ++q) {
    int row = q * 32 + ldsrow;
    int kb = kslot ^ ((row & 7) << 4);
    int r = mt * 128 + row;
    long arow;
    if (!se) arow = (r < cnt) ? (lists[e * T_ + r] >> 1) : 0;
    else arow = r;
    aSrc[q] = (const char*)xb + (size_t)arow * strideB + kb;
    int nrow = nt * 128 + row;
    bSrc[q] = (const char*)B0 + (size_t)nrow * strideB + kb;
  }

  const f32x4 fz = {0.f, 0.f, 0.f, 0.f};
  f32x4 acc[4][4];
#pragma unroll
  for (int i = 0; i < 4; ++i)
#pragma unroll
    for (int j = 0; j < 4; ++j) acc[i][j] = fz;

  const int sw = (lr & 7) << 4;
  constexpr int nks = D_ / 64;   // 16

  for (int ks = 0; ks < nks; ++ks) {
    const int kbo = ks * 128;
#pragma unroll
    for (int q = 0; q < 4; ++q) gl_lds16(aSrc[q] + kbo, smem + q * 4096 + tid * 16);
#pragma unroll
    for (int q = 0; q < 4; ++q) gl_lds16(bSrc[q] + kbo, smem + 16384 + q * 4096 + tid * 16);
    __syncthreads();
    const char* As = smem;
    const char* Bs = smem + 16384;
#pragma unroll
    for (int kk = 0; kk < 2; ++kk) {
      const int ko = kk * 64 + lg * 16;
      short8 af[4];
#pragma unroll
      for (int fm = 0; fm < 4; ++fm) {
        int row = wm * 64 + fm * 16 + lr;
        af[fm] = *(const short8*)(As + row * 128 + (ko ^ sw));
      }
#pragma unroll
      for (int fn = 0; fn < 4; ++fn) {
        int col = wn * 64 + fn * 16 + lr;
        short8 bf = *(const short8*)(Bs + col * 128 + (ko ^ sw));
#pragma unroll
        for (int fm = 0; fm < 4; ++fm)
          acc[fm][fn] = __builtin_amdgcn_mfma_f32_16x16x32_bf16(af[fm], bf, acc[fm][fn], 0, 0, 0);
      }
    }
    __syncthreads();
  }

  const int c0 = 16 * (4 * nt + 2 * wn);
  const int r0 = mt * 128;
#pragma unroll
  for (int fm = 0; fm < 4; ++fm) {
#pragma unroll
    for (int j = 0; j < 4; ++j) {
      const int r = r0 + wm * 64 + fm * 16 + lg * 4 + j;
      if (!se && r >= cnt) continue;
      float h0 = silu(acc[fm][0][j]) * acc[fm][1][j];
      float h1 = silu(acc[fm][2][j]) * acc[fm][3][j];
      if (!se) {
        hb[(size_t)(roff + r) * F_ + c0 + lr] = f2b(h0);
        hb[(size_t)(roff + r) * F_ + c0 + 16 + lr] = f2b(h1);
      } else {
        hs[(size_t)r * FS_ + c0 + lr] = f2b(h0);
        hs[(size_t)r * FS_ + c0 + 16 + lr] = f2b(h1);
      }
    }
  }
}

// MODE 1: expert down (single buffer, (256,4)).
// MODE 3: shared down + combine (dbuf 2-phase, (256,2): grid 512 = 2 blocks/CU).
template <int MODE>
__global__ __launch_bounds__(256, MODE == 3 ? 2 : 4) void moe_gemm(
    const u16* __restrict__ Abase, const u16* __restrict__ B0,
    u16* __restrict__ outb, float* __restrict__ outf,
    const int* __restrict__ counts, const int* __restrict__ lists,
    const float* __restrict__ pw, const float* __restrict__ gate,
    const u16* __restrict__ pairb, int Kdim) {
  extern __shared__ char smem[];
  const int tid = threadIdx.x;
  const int mt = blockIdx.x, nt = blockIdx.y, e = blockIdx.z;

  int cnt = 0;
  const u16* A = Abase;
  if constexpr (MODE == 1) {
    int roff;
    prefix16(counts, e, cnt, roff);
    if (mt * 128 >= cnt) return;
    A = Abase + (size_t)roff * Kdim;
    B0 += (size_t)e * D_ * F_;
  }

  const int lane = tid & 63, wid = tid >> 6;
  const int wm = wid >> 1, wn = wid & 1;
  const int lr = lane & 15, lg = lane >> 4;
  const int ldsrow = tid >> 3;
  const int kslot = (tid & 7) << 4;
  const size_t strideB = (size_t)Kdim * 2;
  const char* aSrc[4]; const char* bSrc[4];
#pragma unroll
  for (int q = 0; q < 4; ++q) {
    int row = q * 32 + ldsrow;
    int kb = kslot ^ ((row & 7) << 4);
    long arow;
    if constexpr (MODE == 1) {
      int r = mt * 128 + row;
      arow = (r < cnt) ? r : (cnt - 1);
    } else {
      arow = mt * 128 + row;
    }
    aSrc[q] = (const char*)A + (size_t)arow * strideB + kb;
    int nrow = nt * 128 + row;
    bSrc[q] = (const char*)B0 + (size_t)nrow * strideB + kb;
  }

  const f32x4 fz = {0.f, 0.f, 0.f, 0.f};
  f32x4 acc[4][4];
#pragma unroll
  for (int i = 0; i < 4; ++i)
#pragma unroll
    for (int j = 0; j < 4; ++j) acc[i][j] = fz;

  const int nks = Kdim >> 6;
  const int sw = (lr & 7) << 4;

  if constexpr (MODE == 3) {
    {
      char* dst = smem;
#pragma unroll
      for (int q = 0; q < 4; ++q) gl_lds16(aSrc[q], dst + q * 4096 + tid * 16);
#pragma unroll
      for (int q = 0; q < 4; ++q) gl_lds16(bSrc[q], dst + 16384 + q * 4096 + tid * 16);
    }
    __syncthreads();
    int cur = 0;
    for (int ks = 0; ks < nks; ++ks) {
      if (ks + 1 < nks) {
        const int kbo = (ks + 1) * 128;
        char* dst = smem + (cur ^ 1) * 32768;
#pragma unroll
        for (int q = 0; q < 4; ++q) gl_lds16(aSrc[q] + kbo, dst + q * 4096 + tid * 16);
#pragma unroll
        for (int q = 0; q < 4; ++q) gl_lds16(bSrc[q] + kbo, dst + 16384 + q * 4096 + tid * 16);
      }
      const char* As = smem + cur * 32768;
      const char* Bs = As + 16384;
#pragma unroll
      for (int kk = 0; kk < 2; ++kk) {
        const int ko = kk * 64 + lg * 16;
        short8 af[4];
#pragma unroll
        for (int fm = 0; fm < 4; ++fm) {
          int row = wm * 64 + fm * 16 + lr;
          af[fm] = *(const short8*)(As + row * 128 + (ko ^ sw));
        }
#pragma unroll
        for (int fn = 0; fn < 4; ++fn) {
          int col = wn * 64 + fn * 16 + lr;
          short8 bf = *(const short8*)(Bs + col * 128 + (ko ^ sw));
#pragma unroll
          for (int fm = 0; fm < 4; ++fm)
            acc[fm][fn] = __builtin_amdgcn_mfma_f32_16x16x32_bf16(af[fm], bf, acc[fm][fn], 0, 0, 0);
        }
      }
      __syncthreads();
      cur ^= 1;
    }
  } else {
    for (int ks = 0; ks < nks; ++ks) {
      const int kbo = ks * 128;
#pragma unroll
      for (int q = 0; q < 4; ++q) gl_lds16(aSrc[q] + kbo, smem + q * 4096 + tid * 16);
#pragma unroll
      for (int q = 0; q < 4; ++q) gl_lds16(bSrc[q] + kbo, smem + 16384 + q * 4096 + tid * 16);
      __syncthreads();
      const char* As = smem;
      const char* Bs = smem + 16384;
#pragma unroll
      for (int kk = 0; kk < 2; ++kk) {
        const int ko = kk * 64 + lg * 16;
        short8 af[4];
#pragma unroll
        for (int fm = 0; fm < 4; ++fm) {
          int row = wm * 64 + fm * 16 + lr;
          af[fm] = *(const short8*)(As + row * 128 + (ko ^ sw));
        }
#pragma unroll
        for (int fn = 0; fn < 4; ++fn) {
          int col = wn * 64 + fn * 16 + lr;
          short8 bf = *(const short8*)(Bs + col * 128 + (ko ^ sw));
#pragma unroll
          for (int fm = 0; fm < 4; ++fm)
            acc[fm][fn] = __builtin_amdgcn_mfma_f32_16x16x32_bf16(af[fm], bf, acc[fm][fn], 0, 0, 0);
        }
      }
      __syncthreads();
    }
  }

  const int r0 = mt * 128;
#pragma unroll
  for (int fm = 0; fm < 4; ++fm) {
#pragma unroll
    for (int j = 0; j < 4; ++j) {
      const int rowt = wm * 64 + fm * 16 + lg * 4 + j;
      const int r = r0 + rowt;
      if constexpr (MODE == 1) {
        if (r >= cnt) continue;
      }
      int slot = 0;
      float rsc = 0.f;
      if constexpr (MODE == 1) { slot = lists[e * T_ + r]; rsc = pw[slot]; }
      if constexpr (MODE == 3) rsc = gate[r];
#pragma unroll
      for (int fn = 0; fn < 4; ++fn) {
        const int c = nt * 128 + wn * 64 + fn * 16 + lr;
        float v = acc[fm][fn][j];
        if constexpr (MODE == 1) {
          outb[(size_t)slot * D_ + c] = f2b(rsc * v);
        } else {
          float o = v * rsc + b2f(pairb[(size_t)(2 * r) * D_ + c]) + b2f(pairb[(size_t)(2 * r + 1) * D_ + c]);
          outf[(size_t)r * D_ + c] = o;
        }
      }
    }
  }
}

// ---------------- launch ----------------
extern "C" void kernel_launch(void* const* d_in, const int* in_sizes, int n_in,
                              void* d_out, int out_size, void* d_ws, size_t ws_size,
                              hipStream_t stream) {
  const float* x   = (const float*)d_in[0];
  const float* rw  = (const float*)d_in[1];
  const float* Wg  = (const float*)d_in[2];
  const float* Wu  = (const float*)d_in[3];
  const float* Wd  = (const float*)d_in[4];
  const float* Sg  = (const float*)d_in[5];
  const float* Su  = (const float*)d_in[6];
  const float* Sd  = (const float*)d_in[7];
  const float* sgw = (const float*)d_in[8];
  float* out = (float*)d_out;

  unsigned char* ws = (unsigned char*)d_ws;
  u16* xb    = (u16*)(ws + OFF_XB);
  u16* wgu   = (u16*)(ws + OFF_WGU);
  u16* wdT   = (u16*)(ws + OFF_WDT);
  u16* sgu   = (u16*)(ws + OFF_SGU);
  u16* sdT   = (u16*)(ws + OFF_SDT);
  u16* hb    = (u16*)(ws + OFF_HB);
  u16* hs    = (u16*)(ws + OFF_HS);
  u16* pairb = (u16*)(ws + OFF_PAIR);
  float* pwf   = (float*)(ws + OFF_PW);
  float* gatef = (float*)(ws + OFF_GATE);
  int* cnti    = (int*)(ws + OFF_CNT);
  int* top2i   = (int*)(ws + OFF_TOP2);
  int* listsi  = (int*)(ws + OFF_LIST);

  prep_kernel<<<9728, 256, 0, stream>>>(
      (const float4*)x, (const float4*)rw, (const float4*)sgw,
      top2i, pwf, gatef, (ushort4*)xb,
      Wg, Wu, Wd, Sg, Su, Sd, wgu, wdT, sgu, sdT);
  compact_kernel<<<E_, 1024, 0, stream>>>(top2i, listsi, cnti);

  // fused gate+up: expert tiles [0,2048), shared [2048,4096). K=1024
  gu_gemm<<<4096, 256, 32768, stream>>>(xb, wgu, sgu, hb, hs, cnti, listsi);
  // expert down: K=512, N=1024 (single buffer)
  moe_gemm<1><<<dim3(16, 8, 16), 256, 32768, stream>>>(hb, wdT, pairb, nullptr,
                                                       cnti, listsi, pwf, gatef, nullptr, 512);
  // shared down + final combine: K=2048, N=1024 (dbuf 2-phase)
  moe_gemm<3><<<dim3(64, 8, 1), 256, 65536, stream>>>(hs, sdT, nullptr, out,
                                                      cnti, listsi, pwf, gatef, pairb, 2048);

  (void)in_sizes; (void)n_in; (void)out_size; (void)ws_size;
}